// Round 5
// baseline (67.207 us; speedup 1.0000x reference)
//
#include <hip/hip_runtime.h>

// CenterWeightedCIoULoss: mean over N matched pairs. 128 MiB in, 4 B out.
// R4: (1) inline-asm global_load_dwordx4 batch (8 in flight/thread) —
//     sched_barrier alone did NOT hold loads live (VGPR stayed 28 in R3).
//     (2) single kernel + fire-and-forget pre-scaled atomicAdd (no fence/
//     counter chain — that was R2's mistake) + 4B memset for determinism.

#define EPSF 1e-7f
#define UNROLL 4
#define BLOCK 256
#define TILE (BLOCK * UNROLL)

__device__ __forceinline__ float fast_rcp(float x) {
    return __builtin_amdgcn_rcpf(x);
}

// Forced vector load: SGPR base + VGPR byte-offset form.
__device__ __forceinline__ float4 gload4(unsigned long long sbase, unsigned voff) {
    float4 r;
    asm volatile("global_load_dwordx4 %0, %1, %2"
                 : "=v"(r)
                 : "v"(voff), "s"(sbase)
                 : "memory");
    return r;
}

__device__ __forceinline__ float ciou_elem(float4 p, float4 t) {
    const float px1 = p.x, py1 = p.y, px2 = p.z, py2 = p.w;
    const float tx1 = t.x, ty1 = t.y, tx2 = t.z, ty2 = t.w;

    float iw = fminf(px2, tx2) - fmaxf(px1, tx1);
    float ih = fminf(py2, ty2) - fmaxf(py1, ty1);
    iw = fmaxf(iw, 0.f);
    ih = fmaxf(ih, 0.f);
    const float inter  = iw * ih;
    const float pw = px2 - px1, ph = py2 - py1;
    const float tw = tx2 - tx1, th = ty2 - ty1;
    const float p_area = pw * ph;
    const float t_area = tw * th;
    const float iou = inter * fast_rcp(p_area + t_area - inter + EPSF);

    const float dcx = 0.5f * ((px1 + px2) - (tx1 + tx2));
    const float dcy = 0.5f * ((py1 + py2) - (ty1 + ty2));
    const float center_dist_sq = dcx * dcx + dcy * dcy;
    const float cw = fmaxf(px2, tx2) - fminf(px1, tx1);
    const float ch = fmaxf(py2, ty2) - fminf(py1, ty1);
    const float c_diag_sq = cw * cw + ch * ch + EPSF;  // eps twice: faithful
    const float center_term = center_dist_sq * fast_rcp(c_diag_sq + EPSF);

    const float sw = (pw - tw) * fast_rcp(tw + EPSF);
    const float sh = (ph - th) * fast_rcp(th + EPSF);
    const float size_term = sw * sw + sh * sh;

    return (1.f - iou) + 2.f * center_term + size_term;
}

template <bool TAIL>
__global__ __launch_bounds__(BLOCK) void ciou_fused_kernel(
        const float4* __restrict__ pred,
        const float4* __restrict__ targ,
        float* __restrict__ out, int n, float inv_n) {
    float acc0 = 0.f, acc1 = 0.f;

    if (!TAIL) {
        // Byte offset of this thread's first element; each u-step advances
        // BLOCK elements = BLOCK*16 bytes. All offsets fit 32 bits (64 MB buf).
        const unsigned base = (blockIdx.x * TILE + threadIdx.x) * 16u;
        float4 p[UNROLL], t[UNROLL];
        #pragma unroll
        for (int u = 0; u < UNROLL; ++u) {
            const unsigned off = base + (unsigned)(u * BLOCK * 16);
            p[u] = gload4((unsigned long long)pred, off);
            t[u] = gload4((unsigned long long)targ, off);
        }
        asm volatile("s_waitcnt vmcnt(0)" ::: "memory");
        __builtin_amdgcn_sched_barrier(0);

        #pragma unroll
        for (int u = 0; u < UNROLL; u += 2) {
            acc0 += ciou_elem(p[u],     t[u]);
            acc1 += ciou_elem(p[u + 1], t[u + 1]);
        }
    } else {
        const int base = blockIdx.x * TILE + threadIdx.x;
        #pragma unroll
        for (int u = 0; u < UNROLL; ++u) {
            const int idx = base + u * BLOCK;
            if (idx < n) acc0 += ciou_elem(pred[idx], targ[idx]);
        }
    }
    float acc = acc0 + acc1;

    // wave reduce (64-wide) then cross-wave LDS reduce
    #pragma unroll
    for (int off = 32; off > 0; off >>= 1)
        acc += __shfl_down(acc, off, 64);

    __shared__ float lds_ws[BLOCK / 64];
    const int lane = threadIdx.x & 63;
    const int wave = threadIdx.x >> 6;
    if (lane == 0) lds_ws[wave] = acc;
    __syncthreads();

    if (threadIdx.x == 0) {
        float blk = 0.f;
        #pragma unroll
        for (int w = 0; w < BLOCK / 64; ++w) blk += lds_ws[w];
        // fire-and-forget: no fence, no counter, block retires immediately
        atomicAdd(out, blk * inv_n);
    }
}

extern "C" void kernel_launch(void* const* d_in, const int* in_sizes, int n_in,
                              void* d_out, int out_size, void* d_ws, size_t ws_size,
                              hipStream_t stream) {
    const float4* pred = (const float4*)d_in[0];
    const float4* targ = (const float4*)d_in[1];
    float* out = (float*)d_out;

    const int n = in_sizes[0] / 4;  // number of boxes (4,194,304)
    const int grid = (n + TILE - 1) / TILE;
    const float inv_n = 1.0f / (float)n;

    // out accumulates via atomics -> must start at 0 every call (replays!)
    hipMemsetAsync(d_out, 0, sizeof(float), stream);

    if (n % TILE == 0) {
        ciou_fused_kernel<false><<<grid, BLOCK, 0, stream>>>(pred, targ, out, n, inv_n);
    } else {
        ciou_fused_kernel<true><<<grid, BLOCK, 0, stream>>>(pred, targ, out, n, inv_n);
    }
}

// Round 6
// 27.496 us; speedup vs baseline: 2.4443x; 2.4443x over previous
//
#include <hip/hip_runtime.h>

// CenterWeightedCIoULoss: mean over N matched pairs. 128 MiB in, 4 B out.
// R5: software-pipelined double-buffer. R1/R3/R4 all show VGPR=28 -> the
// compiler collapses one-shot load batches to load->use pairs (2-deep MLP).
// Fix: persistent blocks, runtime-trip loop, stage s+1 loads issued while
// computing stage s; live-across-backedge buffers force VGPR allocation.
// Reverted: asm loads + vmcnt(0) drain (stalled full latency per block),
// same-address atomics (R2/R4 tails). Two kernels again.

#define EPSF 1e-7f
#define BLOCK 256
#define U 2                       // elems per thread per stage
#define STAGE_ELEMS (BLOCK * U)   // 512 elems per block per stage
#define GRID 2048                 // 8 blocks/CU on 256 CUs

__device__ __forceinline__ float fast_rcp(float x) {
    return __builtin_amdgcn_rcpf(x);
}

__device__ __forceinline__ float ciou_elem(float4 p, float4 t) {
    const float px1 = p.x, py1 = p.y, px2 = p.z, py2 = p.w;
    const float tx1 = t.x, ty1 = t.y, tx2 = t.z, ty2 = t.w;

    float iw = fminf(px2, tx2) - fmaxf(px1, tx1);
    float ih = fminf(py2, ty2) - fmaxf(py1, ty1);
    iw = fmaxf(iw, 0.f);
    ih = fmaxf(ih, 0.f);
    const float inter  = iw * ih;
    const float pw = px2 - px1, ph = py2 - py1;
    const float tw = tx2 - tx1, th = ty2 - ty1;
    const float p_area = pw * ph;
    const float t_area = tw * th;
    const float iou = inter * fast_rcp(p_area + t_area - inter + EPSF);

    const float dcx = 0.5f * ((px1 + px2) - (tx1 + tx2));
    const float dcy = 0.5f * ((py1 + py2) - (ty1 + ty2));
    const float center_dist_sq = dcx * dcx + dcy * dcy;
    const float cw = fmaxf(px2, tx2) - fminf(px1, tx1);
    const float ch = fmaxf(py2, ty2) - fminf(py1, ty1);
    const float c_diag_sq = cw * cw + ch * ch + EPSF;  // eps twice: faithful
    const float center_term = center_dist_sq * fast_rcp(c_diag_sq + EPSF);

    const float sw = (pw - tw) * fast_rcp(tw + EPSF);
    const float sh = (ph - th) * fast_rcp(th + EPSF);
    const float size_term = sw * sw + sh * sh;

    return (1.f - iou) + 2.f * center_term + size_term;
}

__device__ __forceinline__ float wave_block_reduce(float acc, float* lds_ws) {
    #pragma unroll
    for (int off = 32; off > 0; off >>= 1)
        acc += __shfl_down(acc, off, 64);
    const int lane = threadIdx.x & 63;
    const int wave = threadIdx.x >> 6;
    if (lane == 0) lds_ws[wave] = acc;
    __syncthreads();
    float s = 0.f;
    if (threadIdx.x == 0) {
        #pragma unroll
        for (int w = 0; w < BLOCK / 64; ++w) s += lds_ws[w];
    }
    return s;  // valid in thread 0 only
}

// Pipelined kernel: requires n == GRID * nstages * STAGE_ELEMS, nstages even.
__global__ __launch_bounds__(BLOCK) void ciou_partial_pipe(
        const float4* __restrict__ pred,
        const float4* __restrict__ targ,
        float* __restrict__ partial, int nstages) {
    const long long blockBase =
        (long long)blockIdx.x * nstages * STAGE_ELEMS + threadIdx.x;
    const float4* pb = pred + blockBase;
    const float4* tb = targ + blockBase;

    float4 pA[U], tA[U], pB[U], tB[U];

#define LOAD(PX, TX, s)                                   \
    _Pragma("unroll")                                     \
    for (int u = 0; u < U; ++u) {                         \
        PX[u] = pb[(s) * STAGE_ELEMS + u * BLOCK];        \
        TX[u] = tb[(s) * STAGE_ELEMS + u * BLOCK];        \
    }

    float acc0 = 0.f, acc1 = 0.f;
#define COMPUTE(PX, TX)                                   \
    acc0 += ciou_elem(PX[0], TX[0]);                      \
    acc1 += ciou_elem(PX[1], TX[1]);

    // prologue: 2 stages in flight
    LOAD(pA, tA, 0)
    LOAD(pB, tB, 1)

    // steady state: consume one stage, immediately refill it 2 ahead.
    // nstages is runtime -> loop survives, buffers live across backedge.
    int s = 2;
    for (; s < nstages; s += 2) {
        COMPUTE(pA, tA)
        LOAD(pA, tA, s)
        COMPUTE(pB, tB)
        LOAD(pB, tB, s + 1)
    }
    // epilogue: drain the last two stages
    COMPUTE(pA, tA)
    COMPUTE(pB, tB)

#undef LOAD
#undef COMPUTE

    float acc = acc0 + acc1;
    __shared__ float lds_ws[BLOCK / 64];
    const float blk = wave_block_reduce(acc, lds_ws);
    if (threadIdx.x == 0) partial[blockIdx.x] = blk;
}

// Generic fallback: grid-stride, any n. Still writes GRID partials.
__global__ __launch_bounds__(BLOCK) void ciou_partial_generic(
        const float4* __restrict__ pred,
        const float4* __restrict__ targ,
        float* __restrict__ partial, int n) {
    const int tid = blockIdx.x * BLOCK + threadIdx.x;
    const int stride = GRID * BLOCK;
    float acc = 0.f;
    for (int i = tid; i < n; i += stride)
        acc += ciou_elem(pred[i], targ[i]);
    __shared__ float lds_ws[BLOCK / 64];
    const float blk = wave_block_reduce(acc, lds_ws);
    if (threadIdx.x == 0) partial[blockIdx.x] = blk;
}

__global__ __launch_bounds__(BLOCK) void ciou_final_kernel(
        const float* __restrict__ partial, int nparts,
        float* __restrict__ out, float inv_n) {
    const float4* pv = (const float4*)partial;  // nparts % 4 == 0
    const int nvec = nparts >> 2;
    float acc = 0.f;
    for (int i = threadIdx.x; i < nvec; i += BLOCK) {
        const float4 v = pv[i];
        acc += (v.x + v.y) + (v.z + v.w);
    }
    __shared__ float lds_ws[BLOCK / 64];
    const float s = wave_block_reduce(acc, lds_ws);
    if (threadIdx.x == 0) out[0] = s * inv_n;
}

extern "C" void kernel_launch(void* const* d_in, const int* in_sizes, int n_in,
                              void* d_out, int out_size, void* d_ws, size_t ws_size,
                              hipStream_t stream) {
    const float4* pred = (const float4*)d_in[0];
    const float4* targ = (const float4*)d_in[1];
    float* out = (float*)d_out;
    float* partial = (float*)d_ws;

    const int n = in_sizes[0] / 4;  // number of boxes (4,194,304)
    const int per_block_stage = STAGE_ELEMS;
    const long long denom = (long long)GRID * per_block_stage;
    const int nstages = (int)(n / denom);  // 4 at N=4M

    if ((long long)nstages * denom == n && nstages >= 2 && (nstages & 1) == 0) {
        ciou_partial_pipe<<<GRID, BLOCK, 0, stream>>>(pred, targ, partial, nstages);
    } else {
        ciou_partial_generic<<<GRID, BLOCK, 0, stream>>>(pred, targ, partial, n);
    }
    ciou_final_kernel<<<1, BLOCK, 0, stream>>>(partial, GRID, out, 1.0f / (float)n);
}